// Round 1
// baseline (644.050 us; speedup 1.0000x reference)
//
#include <hip/hip_runtime.h>
#include <stdint.h>

typedef unsigned short ushort_t;
typedef __attribute__((ext_vector_type(8))) short bfrag;   // 8 x bf16 (bit pattern)
typedef __attribute__((ext_vector_type(4))) float ffrag;   // mfma f32x4 acc

#define B_  32
#define K_  8
#define N_  4096
#define D_  256
#define H_  4
#define DH_ 64

__device__ __forceinline__ ushort_t f2bf(float f) {
  unsigned int u = __builtin_bit_cast(unsigned int, f);
  u += 0x7FFFu + ((u >> 16) & 1u);           // round-nearest-even
  return (ushort_t)(u >> 16);
}

// ---------------- per-row mean/rstd of x ----------------
__global__ __launch_bounds__(256) void k_stats(const float* __restrict__ x,
                                               float2* __restrict__ stats) {
  int row = blockIdx.x * 4 + (threadIdx.x >> 6);
  int lane = threadIdx.x & 63;
  const float4* xr = (const float4*)(x + (size_t)row * 256);
  float4 v = xr[lane];
  float s = v.x + v.y + v.z + v.w;
  float q = v.x*v.x + v.y*v.y + v.z*v.z + v.w*v.w;
  #pragma unroll
  for (int off = 32; off >= 1; off >>= 1) { s += __shfl_xor(s, off); q += __shfl_xor(q, off); }
  if (lane == 0) {
    float m = s * (1.f/256.f);
    float var = q * (1.f/256.f) - m * m;
    stats[row] = make_float2(m, rsqrtf(var + 1e-5f));
  }
}

// ---------------- prep: wkv' = ln_w * [Wk;Wv] (bf16), c1=rowsum(wkv'), c2=rowdot(ln_b, W) ----------------
__global__ __launch_bounds__(256) void k_prep_wkv(const float* __restrict__ Wk, const float* __restrict__ Wv,
                                                  const float* __restrict__ lnw, const float* __restrict__ lnb,
                                                  ushort_t* __restrict__ wkv,
                                                  float* __restrict__ c1, float* __restrict__ c2) {
  int n = blockIdx.x;           // 0..511
  int i = threadIdx.x;          // 0..255
  float wv = (n < 256) ? Wk[n*256 + i] : Wv[(n-256)*256 + i];
  float wp = lnw[i] * wv;
  wkv[n*256 + i] = f2bf(wp);
  float p1 = wp, p2 = lnb[i] * wv;
  #pragma unroll
  for (int off = 32; off >= 1; off >>= 1) { p1 += __shfl_xor(p1, off); p2 += __shfl_xor(p2, off); }
  __shared__ float r1[4], r2[4];
  int w = threadIdx.x >> 6;
  if ((threadIdx.x & 63) == 0) { r1[w] = p1; r2[w] = p2; }
  __syncthreads();
  if (threadIdx.x == 0) { c1[n] = r1[0]+r1[1]+r1[2]+r1[3]; c2[n] = r2[0]+r2[1]+r2[2]+r2[3]; }
}

// ---------------- prep: Wfused = Wih @ Wo  ([768,256]) ----------------
__global__ __launch_bounds__(256) void k_prep_wf(const float* __restrict__ Wih, const float* __restrict__ Wo,
                                                 float* __restrict__ Wf) {
  int j = blockIdx.x;   // 0..767
  int i = threadIdx.x;  // 0..255
  __shared__ float row[256];
  row[i] = Wih[j*256 + i];
  __syncthreads();
  float acc = 0.f;
  #pragma unroll 8
  for (int t = 0; t < 256; ++t) acc += row[t] * Wo[t*256 + i];
  Wf[j*256 + i] = acc;
}

// ---------------- shared helpers (8x256 LDS row LN, q projection) ----------------
__device__ __forceinline__ void row_ln_256(float (*S)[256], float (*L)[256],
                                           const float* __restrict__ w, const float* __restrict__ b, int t) {
  int k = t >> 5, ln = t & 31;
  float s = 0.f, q = 0.f;
  #pragma unroll
  for (int j = 0; j < 8; ++j) { float v = S[k][ln + j*32]; s += v; q += v*v; }
  #pragma unroll
  for (int off = 16; off >= 1; off >>= 1) { s += __shfl_xor(s, off); q += __shfl_xor(q, off); }
  float m = s * (1.f/256.f);
  float rstd = rsqrtf(q * (1.f/256.f) - m*m + 1e-5f);
  #pragma unroll
  for (int j = 0; j < 8; ++j) {
    int c = ln + j*32;
    L[k][c] = (S[k][c] - m) * rstd * w[c] + b[c];
  }
}

__device__ __forceinline__ void qproj(float (*L)[256], const float* __restrict__ Wq,
                                      ushort_t* __restrict__ qbuf, int b, int t) {
  int c = t;
  const float4* Wrow = (const float4*)(Wq + (size_t)c * 256);
  float acc[8];
  #pragma unroll
  for (int k = 0; k < 8; ++k) acc[k] = 0.f;
  for (int i = 0; i < 64; ++i) {
    float4 wv = Wrow[i];
    #pragma unroll
    for (int k = 0; k < 8; ++k) {
      float4 xv = *((const float4*)&L[k][0] + i);
      acc[k] = fmaf(xv.x, wv.x, fmaf(xv.y, wv.y, fmaf(xv.z, wv.z, fmaf(xv.w, wv.w, acc[k]))));
    }
  }
  int h = c >> 6, dh = c & 63;
  ushort_t* dst = qbuf + ((size_t)(b*4 + h) * 16) * 64 + dh;
  #pragma unroll
  for (int k = 0; k < 8; ++k) dst[k*64] = f2bf(acc[k] * 0.125f);  // SCALE folded in
  #pragma unroll
  for (int k = 8; k < 16; ++k) dst[k*64] = 0;                     // zero-pad rows 8..15
}

// ---------------- init: slots = mu + exp(log_sigma)*noise; q0 ----------------
__global__ __launch_bounds__(256) void k_init(const float* __restrict__ noise, const float* __restrict__ mu,
                                              const float* __restrict__ lsig, float* __restrict__ slots,
                                              const float* __restrict__ nsw, const float* __restrict__ nsb,
                                              const float* __restrict__ Wq, ushort_t* __restrict__ qbuf) {
  int b = blockIdx.x, t = threadIdx.x;
  __shared__ float S[8][256];
  __shared__ float L[8][256];
  float e = __expf(lsig[t]);
  float m = mu[t];
  #pragma unroll
  for (int k = 0; k < 8; ++k) {
    float v = m + e * noise[((size_t)(b*8+k))*256 + t];
    S[k][t] = v;
    slots[((size_t)(b*8+k))*256 + t] = v;
  }
  __syncthreads();
  row_ln_256(S, L, nsw, nsb, t);
  __syncthreads();
  qproj(L, Wq, qbuf, b, t);
}

// ---------------- big GEMM: [131072,256]x[512,256]^T -> kf [B,H,N,64] bf16, vf^T [B,H,64,N] bf16 ----------------
__global__ __launch_bounds__(256, 2) void k_gemm(const float* __restrict__ x, const float2* __restrict__ stats,
                                                 const ushort_t* __restrict__ wkv,
                                                 const float* __restrict__ c1, const float* __restrict__ c2,
                                                 ushort_t* __restrict__ kf, ushort_t* __restrict__ vfT) {
  int mb = blockIdx.x, cb = blockIdx.y;
  int t = threadIdx.x;
  int w = t >> 6, l = t & 63;
  __shared__ uint4 ldsv[4096];              // 64 KiB: A dbuf @0/16384, B dbuf @32768/49152
  char* lds = (char*)ldsv;
  const int m0 = mb * 128;
  const int col0 = cb * 128;

  int r0 = t >> 1, half = t & 1;
  float4 xa[8];
  uint4 wb[4];

  auto loadA = [&](int s) {
    const float4* src = (const float4*)(x + (size_t)(m0 + r0) * 256 + s*64 + half*32);
    #pragma unroll
    for (int i = 0; i < 8; ++i) xa[i] = src[i];
  };
  auto loadB = [&](int s) {
    const uint4* src = (const uint4*)(wkv + (size_t)(col0 + r0) * 256 + s*64 + half*32);
    #pragma unroll
    for (int i = 0; i < 4; ++i) wb[i] = src[i];
  };
  auto writeA = [&](char* Ab) {
    #pragma unroll
    for (int i = 0; i < 4; ++i) {
      float4 a = xa[2*i], b2 = xa[2*i+1];
      union { ushort_t us[8]; uint4 v; } u;
      u.us[0]=f2bf(a.x);  u.us[1]=f2bf(a.y);  u.us[2]=f2bf(a.z);  u.us[3]=f2bf(a.w);
      u.us[4]=f2bf(b2.x); u.us[5]=f2bf(b2.y); u.us[6]=f2bf(b2.z); u.us[7]=f2bf(b2.w);
      int byte = (r0*128 + half*64 + i*16) ^ ((r0 & 7) << 4);
      *(uint4*)(Ab + byte) = u.v;
    }
  };
  auto writeB = [&](char* Bb) {
    #pragma unroll
    for (int i = 0; i < 4; ++i) {
      int byte = (r0*128 + half*64 + i*16) ^ ((r0 & 7) << 4);
      *(uint4*)(Bb + byte) = wb[i];
    }
  };

  ffrag acc[4][4];
  #pragma unroll
  for (int i = 0; i < 4; ++i)
    #pragma unroll
    for (int j = 0; j < 4; ++j) acc[i][j] = (ffrag){0.f,0.f,0.f,0.f};

  int wm = w & 1, wn = w >> 1;
  int lrow = l & 15, lk = (l >> 4) * 8;

  loadA(0); loadB(0);
  writeA(lds + 0); writeB(lds + 32768);
  __syncthreads();

  for (int s = 0; s < 4; ++s) {
    char* Ac = lds + ((s & 1) ? 16384 : 0);
    char* Bc = lds + 32768 + ((s & 1) ? 16384 : 0);
    if (s < 3) { loadA(s+1); loadB(s+1); }   // prefetch in flight during MFMA
    #pragma unroll
    for (int kk = 0; kk < 2; ++kk) {
      bfrag af[4], bf[4];
      #pragma unroll
      for (int i = 0; i < 4; ++i) {
        int row = wm*64 + i*16 + lrow;
        int byte = (row*128 + (kk*32 + lk)*2) ^ ((row & 7) << 4);
        af[i] = *(const bfrag*)(Ac + byte);
      }
      #pragma unroll
      for (int j = 0; j < 4; ++j) {
        int row = wn*64 + j*16 + lrow;
        int byte = (row*128 + (kk*32 + lk)*2) ^ ((row & 7) << 4);
        bf[j] = *(const bfrag*)(Bc + byte);
      }
      #pragma unroll
      for (int i = 0; i < 4; ++i)
        #pragma unroll
        for (int j = 0; j < 4; ++j)
          acc[i][j] = __builtin_amdgcn_mfma_f32_16x16x32_bf16(af[i], bf[j], acc[i][j], 0, 0, 0);
    }
    if (s < 3) {
      char* An = lds + ((s & 1) ? 0 : 16384);
      char* Bn = lds + 32768 + ((s & 1) ? 0 : 16384);
      writeA(An); writeB(Bn);
    }
    __syncthreads();
  }

  // Epilogue: val = rstd_m*(acc - mean_m*c1[n]) + c2[n]
  int g = l >> 4, nl = l & 15;
  int b = m0 >> 12;            // m0/4096
  int nx0 = m0 & 4095;
  if (cb < 2) {
    // kf path: Ct[m][col], pitch 136 elems
    char* Ct = lds;
    #pragma unroll
    for (int i = 0; i < 4; ++i) {
      #pragma unroll
      for (int j = 0; j < 4; ++j) {
        int coll = wn*64 + j*16 + nl;
        float cc1 = c1[col0 + coll], cc2 = c2[col0 + coll];
        #pragma unroll
        for (int r = 0; r < 4; ++r) {
          int ml = wm*64 + i*16 + g*4 + r;
          float2 st = stats[m0 + ml];
          float val = st.y * (acc[i][j][r] - st.x * cc1) + cc2;
          *(ushort_t*)(Ct + (ml*136 + coll)*2) = f2bf(val);
        }
      }
    }
    __syncthreads();
    int m = t >> 1, hh = t & 1;
    int h = cb*2 + hh;
    ushort_t* dst = kf + ((size_t)((b*4 + h)*4096 + nx0 + m)) * 64;
    const char* srcr = Ct + m*272 + hh*128;
    #pragma unroll
    for (int jj = 0; jj < 8; ++jj)
      ((uint4*)dst)[jj] = *(const uint4*)(srcr + jj*16);
  } else {
    // vf path (transposed): CT[col][m], pitch 136 elems
    char* Ct = lds;
    #pragma unroll
    for (int i = 0; i < 4; ++i) {
      int mlbase = wm*64 + i*16 + g*4;
      #pragma unroll
      for (int j = 0; j < 4; ++j) {
        int coll = wn*64 + j*16 + nl;
        float cc1 = c1[col0 + coll], cc2 = c2[col0 + coll];
        ushort_t us[4];
        #pragma unroll
        for (int r = 0; r < 4; ++r) {
          float2 st = stats[m0 + mlbase + r];
          us[r] = f2bf(st.y * (acc[i][j][r] - st.x * cc1) + cc2);
        }
        uint2 pk = make_uint2((unsigned)us[0] | ((unsigned)us[1] << 16),
                              (unsigned)us[2] | ((unsigned)us[3] << 16));
        *(uint2*)(Ct + coll*272 + mlbase*2) = pk;
      }
    }
    __syncthreads();
    int colt = t >> 1, hh = t & 1;
    int h = (cb - 2)*2 + (colt >> 6);
    int dh = colt & 63;
    ushort_t* dst = vfT + ((size_t)((b*4 + h)*64 + dh)) * 4096 + nx0 + hh*64;
    const char* srcr = Ct + colt*272 + hh*128;
    #pragma unroll
    for (int jj = 0; jj < 8; ++jj)
      ((uint4*)dst)[jj] = *(const uint4*)(srcr + jj*16);
  }
}

// ---------------- attention: per (bh, 256-key chunk) ----------------
__global__ __launch_bounds__(256, 2) void k_attn(const ushort_t* __restrict__ q, const ushort_t* __restrict__ kf,
                                                 const ushort_t* __restrict__ vfT,
                                                 float* __restrict__ updp, float* __restrict__ asump) {
  int split = blockIdx.x;   // 0..15
  int bh = blockIdx.y;      // 0..127
  int n0 = split * 256;
  int t = threadIdx.x, w = t >> 6, l = t & 63;
  __shared__ uint4 ldsv[4736];           // 75776 B
  char* lds = (char*)ldsv;
  char* Kt = lds;                        // [256][128B] swizzled
  char* Vt = lds + 32768;                // [64][512B]  swizzled
  char* Pl = lds + 65536;                // [16][512B]  swizzled
  char* Ql = lds + 73728;                // [16][128B]  swizzled

  { // stage K rows (row-major, contiguous 32KB)
    const uint4* src = (const uint4*)(kf + ((size_t)bh*4096 + n0 + t) * 64);
    #pragma unroll
    for (int i = 0; i < 8; ++i) {
      int byte = (t*128 + i*16) ^ ((t & 7) << 4);
      *(uint4*)(Kt + byte) = src[i];
    }
  }
  { // stage V^T rows
    int d = t >> 2, seg = t & 3;
    const uint4* src = (const uint4*)(vfT + ((size_t)bh*64 + d) * 4096 + n0 + seg*64);
    #pragma unroll
    for (int i = 0; i < 4; ++i) {
      int byte = (d*512 + seg*128 + i*16) ^ ((d & 7) << 4);
      *(uint4*)(Vt + byte) = src[i];
    }
  }
  if (t < 128) { // stage Q (16x64, rows 8..15 pre-zeroed in qbuf)
    int k = t >> 3, seg = t & 7;
    uint4 v = *(const uint4*)(q + ((size_t)bh*16 + k) * 64 + seg*8);
    int byte = (k*128 + seg*16) ^ ((k & 7) << 4);
    *(uint4*)(Ql + byte) = v;
  }
  // zero P rows 8..15 (A-operand padding)
  *(uint4*)(Pl + 4096 + t*16) = make_uint4(0,0,0,0);
  __syncthreads();

  int g = l >> 4, nl = l & 15, lk = g * 8;

  // dots = Q*K^T : each wave does 4 n-tiles of 16
  ffrag dacc[4];
  #pragma unroll
  for (int nt = 0; nt < 4; ++nt) {
    dacc[nt] = (ffrag){0.f,0.f,0.f,0.f};
    #pragma unroll
    for (int kk = 0; kk < 2; ++kk) {
      int qbyte = (nl*128 + (kk*32 + lk)*2) ^ ((nl & 7) << 4);
      bfrag af = *(const bfrag*)(Ql + qbyte);
      int row = w*64 + nt*16 + nl;
      int kbyte = (row*128 + (kk*32 + lk)*2) ^ ((row & 7) << 4);
      bfrag bf = *(const bfrag*)(Kt + kbyte);
      dacc[nt] = __builtin_amdgcn_mfma_f32_16x16x32_bf16(af, bf, dacc[nt], 0, 0, 0);
    }
  }

  // softmax over k (8 slots) per column n; accumulate asum; write P (bf16) to LDS
  float asr0 = 0.f, asr1 = 0.f, asr2 = 0.f, asr3 = 0.f;
  #pragma unroll
  for (int nt = 0; nt < 4; ++nt) {
    float d0 = dacc[nt][0], d1 = dacc[nt][1], d2 = dacc[nt][2], d3 = dacc[nt][3];
    float mx = fmaxf(fmaxf(d0, d1), fmaxf(d2, d3));
    mx = fmaxf(mx, __shfl_xor(mx, 16));
    float p0 = __expf(d0 - mx), p1 = __expf(d1 - mx), p2 = __expf(d2 - mx), p3 = __expf(d3 - mx);
    float sden = p0 + p1 + p2 + p3;
    sden += __shfl_xor(sden, 16);
    float inv = 1.f / sden;
    p0 *= inv; p1 *= inv; p2 *= inv; p3 *= inv;
    if (g < 2) {
      asr0 += p0; asr1 += p1; asr2 += p2; asr3 += p3;
      int n = w*64 + nt*16 + nl;
      int k0 = g*4;
      *(ushort_t*)(Pl + (((k0+0)*512 + n*2) ^ (((k0+0)&7) << 4))) = f2bf(p0);
      *(ushort_t*)(Pl + (((k0+1)*512 + n*2) ^ (((k0+1)&7) << 4))) = f2bf(p1);
      *(ushort_t*)(Pl + (((k0+2)*512 + n*2) ^ (((k0+2)&7) << 4))) = f2bf(p2);
      *(ushort_t*)(Pl + (((k0+3)*512 + n*2) ^ (((k0+3)&7) << 4))) = f2bf(p3);
    }
  }
  #pragma unroll
  for (int off = 8; off >= 1; off >>= 1) {
    asr0 += __shfl_xor(asr0, off); asr1 += __shfl_xor(asr1, off);
    asr2 += __shfl_xor(asr2, off); asr3 += __shfl_xor(asr3, off);
  }
  if (g < 2 && nl == 0) {
    float* dst = asump + (((size_t)bh*16 + split)*4 + w)*8 + g*4;
    dst[0] = asr0; dst[1] = asr1; dst[2] = asr2; dst[3] = asr3;
  }
  __syncthreads();

  // upd_partial = P @ V : wave w owns d-tile [w*16, w*16+16)
  ffrag pacc = (ffrag){0.f,0.f,0.f,0.f};
  #pragma unroll
  for (int ni = 0; ni < 8; ++ni) {
    int nn = ni * 32;
    int pbyte = (nl*512 + (nn + lk)*2) ^ ((nl & 7) << 4);
    bfrag af = *(const bfrag*)(Pl + pbyte);
    int d = w*16 + nl;
    int vbyte = (d*512 + (nn + lk)*2) ^ ((d & 7) << 4);
    bfrag bf = *(const bfrag*)(Vt + vbyte);
    pacc = __builtin_amdgcn_mfma_f32_16x16x32_bf16(af, bf, pacc, 0, 0, 0);
  }
  if (g < 2) {
    float* dst = updp + (((size_t)bh*16 + split)*8 + g*4)*64 + w*16 + nl;
    #pragma unroll
    for (int r = 0; r < 4; ++r) dst[r*64] = pacc[r];
  }
}

// ---------------- finalize: upd = sum(partials)/(sum(asum)+eps), merge heads ----------------
__global__ __launch_bounds__(256) void k_fin(const float* __restrict__ updp, const float* __restrict__ asump,
                                             float* __restrict__ upd) {
  int bh = blockIdx.x, t = threadIdx.x;
  __shared__ float asum[8];
  if (t < 8) {
    float a = 0.f;
    for (int s = 0; s < 64; ++s) a += asump[((size_t)bh*64 + s)*8 + t];
    asum[t] = a + 1e-8f;
  }
  __syncthreads();
  int b = bh >> 2, h = bh & 3;
  #pragma unroll
  for (int o = t; o < 512; o += 256) {
    int k = o >> 6, d = o & 63;
    float u = 0.f;
    for (int s = 0; s < 16; ++s) u += updp[(((size_t)bh*16 + s)*8 + k)*64 + d];
    upd[((size_t)(b*8 + k))*256 + h*64 + d] = u / asum[k];
  }
}

// ---------------- U1: gi = upd@Wfused^T + bih ; gh = slots@Whh^T + bhh ----------------
__global__ __launch_bounds__(256) void k_u1(const float* __restrict__ upd, const float* __restrict__ slots,
                                            const float* __restrict__ Wf, const float* __restrict__ Whh,
                                            const float* __restrict__ bih, const float* __restrict__ bhh,
                                            float* __restrict__ gi, float* __restrict__ gh) {
  int cb = blockIdx.x, b = blockIdx.y, t = threadIdx.x;
  int c = cb * 256 + t;                 // 0..1535
  bool isGi = (c < 768);
  __shared__ float X[8][256];
  const float* src = isGi ? upd : slots;
  #pragma unroll
  for (int k = 0; k < 8; ++k) X[k][t] = src[((size_t)(b*8+k))*256 + t];
  __syncthreads();
  int cc = isGi ? c : (c - 768);
  const float* Wrow = (isGi ? Wf : Whh) + (size_t)cc * 256;
  float bias = isGi ? bih[cc] : bhh[cc];
  float acc[8];
  #pragma unroll
  for (int k = 0; k < 8; ++k) acc[k] = bias;
  for (int i = 0; i < 64; ++i) {
    float4 wv = ((const float4*)Wrow)[i];
    #pragma unroll
    for (int k = 0; k < 8; ++k) {
      float4 xv = *((const float4*)&X[k][0] + i);
      acc[k] = fmaf(xv.x, wv.x, fmaf(xv.y, wv.y, fmaf(xv.z, wv.z, fmaf(xv.w, wv.w, acc[k]))));
    }
  }
  float* dst = isGi ? gi : gh;
  #pragma unroll
  for (int k = 0; k < 8; ++k) dst[((size_t)(b*8+k))*768 + cc] = acc[k];
}

// ---------------- U2: GRU + LN + MLP (+ next-iter q) ----------------
__global__ __launch_bounds__(256) void k_u2(const float* __restrict__ gi, const float* __restrict__ gh,
                                            const float* __restrict__ slots_in, float* __restrict__ slots_out,
                                            const float* __restrict__ nmw, const float* __restrict__ nmb,
                                            const float* __restrict__ W1, const float* __restrict__ b1,
                                            const float* __restrict__ W2, const float* __restrict__ b2,
                                            const float* __restrict__ nsw, const float* __restrict__ nsb,
                                            const float* __restrict__ Wq, ushort_t* __restrict__ qbuf, int do_q) {
  int b = blockIdx.x, t = threadIdx.x;
  __shared__ float S[8][256];
  __shared__ float L[8][256];
  __shared__ float H1[8][256];
  // GRU
  #pragma unroll
  for (int k = 0; k < 8; ++k) {
    size_t gb = ((size_t)(b*8+k))*768;
    float ir = gi[gb + t],       hr = gh[gb + t];
    float iz = gi[gb + 256 + t], hz = gh[gb + 256 + t];
    float in_ = gi[gb + 512 + t], hn = gh[gb + 512 + t];
    float r = 1.f / (1.f + __expf(-(ir + hr)));
    float z = 1.f / (1.f + __expf(-(iz + hz)));
    float a = in_ + r * hn;
    float e2 = __expf(-2.f * fabsf(a));
    float nn = (1.f - e2) / (1.f + e2);
    nn = copysignf(nn, a);
    S[k][t] = (1.f - z) * nn + z * slots_in[((size_t)(b*8+k))*256 + t];
  }
  __syncthreads();
  row_ln_256(S, L, nmw, nmb, t);
  __syncthreads();
  { // h1 = relu(L @ W1^T + b1)
    const float4* Wrow = (const float4*)(W1 + (size_t)t * 256);
    float bb = b1[t];
    float acc[8];
    #pragma unroll
    for (int k = 0; k < 8; ++k) acc[k] = bb;
    for (int i = 0; i < 64; ++i) {
      float4 wv = Wrow[i];
      #pragma unroll
      for (int k = 0; k < 8; ++k) {
        float4 xv = *((const float4*)&L[k][0] + i);
        acc[k] = fmaf(xv.x, wv.x, fmaf(xv.y, wv.y, fmaf(xv.z, wv.z, fmaf(xv.w, wv.w, acc[k]))));
      }
    }
    #pragma unroll
    for (int k = 0; k < 8; ++k) H1[k][t] = fmaxf(acc[k], 0.f);
  }
  __syncthreads();
  { // out = S + H1 @ W2^T + b2
    const float4* Wrow = (const float4*)(W2 + (size_t)t * 256);
    float bb = b2[t];
    float acc[8];
    #pragma unroll
    for (int k = 0; k < 8; ++k) acc[k] = bb;
    for (int i = 0; i < 64; ++i) {
      float4 wv = Wrow[i];
      #pragma unroll
      for (int k = 0; k < 8; ++k) {
        float4 xv = *((const float4*)&H1[k][0] + i);
        acc[k] = fmaf(xv.x, wv.x, fmaf(xv.y, wv.y, fmaf(xv.z, wv.z, fmaf(xv.w, wv.w, acc[k]))));
      }
    }
    #pragma unroll
    for (int k = 0; k < 8; ++k) {
      float o = S[k][t] + acc[k];
      slots_out[((size_t)(b*8+k))*256 + t] = o;
      S[k][t] = o;
    }
  }
  __syncthreads();
  if (do_q) {
    row_ln_256(S, L, nsw, nsb, t);
    __syncthreads();
    qproj(L, Wq, qbuf, b, t);
  }
}

// ---------------- launch ----------------
extern "C" void kernel_launch(void* const* d_in, const int* in_sizes, int n_in,
                              void* d_out, int out_size, void* d_ws, size_t ws_size,
                              hipStream_t stream) {
  (void)in_sizes; (void)n_in; (void)out_size; (void)ws_size;
  const float* x     = (const float*)d_in[0];
  const float* noise = (const float*)d_in[1];
  const float* mu    = (const float*)d_in[2];
  const float* lsig  = (const float*)d_in[3];
  const float* ninw  = (const float*)d_in[4];
  const float* ninb  = (const float*)d_in[5];
  const float* nsw   = (const float*)d_in[6];
  const float* nsb   = (const float*)d_in[7];
  const float* nmw   = (const float*)d_in[8];
  const float* nmb   = (const float*)d_in[9];
  const float* Wq    = (const float*)d_in[10];
  const float* Wk    = (const float*)d_in[11];
  const float* Wv    = (const float*)d_in[12];
  const float* Wo    = (const float*)d_in[13];
  const float* Wih   = (const float*)d_in[14];
  const float* Whh   = (const float*)d_in[15];
  const float* bih   = (const float*)d_in[16];
  const float* bhh   = (const float*)d_in[17];
  const float* W1    = (const float*)d_in[18];
  const float* b1    = (const float*)d_in[19];
  const float* W2    = (const float*)d_in[20];
  const float* b2    = (const float*)d_in[21];

  char* ws = (char*)d_ws;
  float2*   stats = (float2*)  (ws + 0);          // 1,048,576
  ushort_t* wkv   = (ushort_t*)(ws + 1048576);    //   262,144
  float*    c1    = (float*)   (ws + 1310720);    //     2,048
  float*    c2    = (float*)   (ws + 1312768);    //     2,048
  float*    Wf    = (float*)   (ws + 1314816);    //   786,432
  float*    slots = (float*)   (ws + 2101248);    //   262,144
  ushort_t* qbuf  = (ushort_t*)(ws + 2363392);    //   262,144
  float*    upd   = (float*)   (ws + 2625536);    //   262,144
  float*    gi    = (float*)   (ws + 2887680);    //   786,432
  float*    gh    = (float*)   (ws + 3674112);    //   786,432
  float*    asump = (float*)   (ws + 4460544);    //   262,144
  float*    updp  = (float*)   (ws + 4722688);    // 4,194,304
  ushort_t* kf    = (ushort_t*)(ws + 8916992);    // 67,108,864
  ushort_t* vfT   = (ushort_t*)(ws + 76025856);   // 67,108,864  (total 143,134,720)

  k_stats   <<<32768, 256, 0, stream>>>(x, stats);
  k_prep_wkv<<<512,   256, 0, stream>>>(Wk, Wv, ninw, ninb, wkv, c1, c2);
  k_prep_wf <<<768,   256, 0, stream>>>(Wih, Wo, Wf);
  k_init    <<<32,    256, 0, stream>>>(noise, mu, lsig, slots, nsw, nsb, Wq, qbuf);
  k_gemm    <<<dim3(1024, 4), 256, 0, stream>>>(x, stats, wkv, c1, c2, kf, vfT);

  float* outp = (float*)d_out;
  for (int it = 0; it < 3; ++it) {
    k_attn<<<dim3(16, 128), 256, 0, stream>>>(qbuf, kf, vfT, updp, asump);
    k_fin <<<128, 256, 0, stream>>>(updp, asump, upd);
    k_u1  <<<dim3(6, 32), 256, 0, stream>>>(upd, slots, Wf, Whh, bih, bhh, gi, gh);
    k_u2  <<<32, 256, 0, stream>>>(gi, gh, slots, (it == 2) ? outp : slots,
                                   nmw, nmb, W1, b1, W2, b2, nsw, nsb, Wq, qbuf, (it < 2) ? 1 : 0);
  }
}